// Round 1
// baseline (386.204 us; speedup 1.0000x reference)
//
#include <hip/hip_runtime.h>
#include <math.h>

// out layout: d_out[0..N) = final_score (f32), d_out[N] = loss (f32)
// ws layout:  pooled f32[N*H] | starts i32[B+1] | seg i32[N]

// ---------------- Kernel 1: masked average pooling over S ----------------
// grid = N blocks, block = H/4 threads (192 for H=768), float4-vectorized.
__global__ void pool_kernel(const float* __restrict__ lhs,
                            const float* __restrict__ mask,
                            float* __restrict__ pooled,
                            int S, int H) {
    const int j  = blockIdx.x;
    const int t  = threadIdx.x;        // 0 .. H/4-1
    const int Hv = H >> 2;
    const float4* row  = (const float4*)(lhs + (size_t)j * S * H);
    const float*  mrow = mask + (size_t)j * S;
    float ax = 0.f, ay = 0.f, az = 0.f, aw = 0.f, msum = 0.f;
#pragma unroll 4
    for (int s = 0; s < S; ++s) {
        float  m = mrow[s];            // uniform address -> L1 broadcast
        float4 v = row[(size_t)s * Hv + t];
        ax = fmaf(v.x, m, ax); ay = fmaf(v.y, m, ay);
        az = fmaf(v.z, m, az); aw = fmaf(v.w, m, aw);
        msum += m;
    }
    const float inv = 1.0f / msum;
    float4 o; o.x = ax * inv; o.y = ay * inv; o.z = az * inv; o.w = aw * inv;
    ((float4*)(pooled + (size_t)j * H))[t] = o;
}

// ---------------- Kernel 2: final_score = [pooler, am, ctc] @ W + b ------
// one wave per row, 4 waves/block.
__global__ void score_kernel(const float* __restrict__ pooler,
                             const float* __restrict__ am,
                             const float* __restrict__ ctc,
                             const float* __restrict__ W,
                             const float* __restrict__ bb,
                             float* __restrict__ out, int N, int H) {
    const int wid  = threadIdx.x >> 6;
    const int lane = threadIdx.x & 63;
    const int i    = blockIdx.x * (blockDim.x >> 6) + wid;
    if (i >= N) return;
    const int Hv = H >> 2;
    const float4* pr = (const float4*)(pooler + (size_t)i * H);
    const float4* Wv = (const float4*)W;
    float acc = 0.f;
    for (int k = lane; k < Hv; k += 64) {
        float4 a = pr[k], w = Wv[k];
        acc += a.x * w.x + a.y * w.y + a.z * w.z + a.w * w.w;
    }
    for (int d = 32; d > 0; d >>= 1) acc += __shfl_xor(acc, d, 64);
    if (lane == 0)
        out[i] = acc + am[i] * W[H] + ctc[i] * W[H + 1] + bb[0];
}

// ---------------- Kernel 3a: group start offsets + zero the loss --------
__global__ void seg_starts_kernel(const int* __restrict__ nbest,
                                  int* __restrict__ starts,
                                  float* __restrict__ loss, int B) {
    if (threadIdx.x == 0) {
        int off = 0;
        for (int g = 0; g < B; ++g) { starts[g] = off; off += nbest[g]; }
        starts[B] = off;
        *loss = 0.f;
    }
}

// ---------------- Kernel 3b: fill per-row segment id ---------------------
__global__ void seg_fill_kernel(const int* __restrict__ starts,
                                int* __restrict__ seg) {
    const int g  = blockIdx.x;
    const int s0 = starts[g], s1 = starts[g + 1];
    for (int idx = s0 + threadIdx.x; idx < s1; idx += blockDim.x) seg[idx] = g;
}

// ---------------- Kernel 4: CE loss over segmented softmax ---------------
// grid = B blocks, 1 wave each.
__global__ void ce_kernel(const float* __restrict__ score,
                          const float* __restrict__ labels,
                          const int* __restrict__ starts,
                          float* __restrict__ loss, int N) {
    const int g    = blockIdx.x;
    const int lane = threadIdx.x;   // block = 64
    const int s0 = starts[g], sz = starts[g + 1] - s0;
    float m = -INFINITY;
    for (int idx = lane; idx < sz; idx += 64) m = fmaxf(m, score[s0 + idx]);
    for (int d = 32; d > 0; d >>= 1) m = fmaxf(m, __shfl_xor(m, d, 64));
    float s = 0.f;
    for (int idx = lane; idx < sz; idx += 64) s += expf(score[s0 + idx] - m);
    for (int d = 32; d > 0; d >>= 1) s += __shfl_xor(s, d, 64);
    const float ls = logf(s);
    float c = 0.f;
    for (int idx = lane; idx < sz; idx += 64) {
        float lb = labels[s0 + idx];
        if (lb != 0.f) c += lb * (score[s0 + idx] - m - ls);
    }
    for (int d = 32; d > 0; d >>= 1) c += __shfl_xor(c, d, 64);
    if (lane == 0) atomicAdd(loss, -c / (float)N);
}

// ---------------- Kernel 5: contrast loss (diagonal only!) ---------------
// Only sim[i, j] for j in i's group is needed for diagonal(sim_prob).
// grid = N blocks, 4 waves; wave w computes dots for j = w, w+4, ...
__global__ void contrast_kernel(const float* __restrict__ pooler,
                                const float* __restrict__ pooled,
                                const int* __restrict__ starts,
                                const int* __restrict__ seg,
                                float* __restrict__ loss, int H, int B) {
    __shared__ float simv[512];
    const int i  = blockIdx.x;
    const int g  = seg[i];
    const int s0 = starts[g], sz = starts[g + 1] - s0;
    const int wid = threadIdx.x >> 6, lane = threadIdx.x & 63;
    const int nw  = blockDim.x >> 6;
    const int Hv  = H >> 2;
    const float4* pi = (const float4*)(pooler + (size_t)i * H);
    for (int j = wid; j < sz; j += nw) {
        const float4* pj = (const float4*)(pooled + (size_t)(s0 + j) * H);
        float acc = 0.f;
        for (int k = lane; k < Hv; k += 64) {
            float4 a = pi[k], b = pj[k];
            acc += a.x * b.x + a.y * b.y + a.z * b.z + a.w * b.w;
        }
        for (int d = 32; d > 0; d >>= 1) acc += __shfl_xor(acc, d, 64);
        if (lane == 0) simv[j] = acc;
    }
    __syncthreads();
    if (wid == 0) {
        float m = -INFINITY;
        for (int idx = lane; idx < sz; idx += 64) m = fmaxf(m, simv[idx]);
        for (int d = 32; d > 0; d >>= 1) m = fmaxf(m, __shfl_xor(m, d, 64));
        float s = 0.f;
        for (int idx = lane; idx < sz; idx += 64) s += expf(simv[idx] - m);
        for (int d = 32; d > 0; d >>= 1) s += __shfl_xor(s, d, 64);
        if (lane == 0) {
            const int p = i - s0;                 // diagonal position in group
            const float prob = expf(simv[p] - m) / s;
            atomicAdd(loss, -prob / (float)B);
        }
    }
}

extern "C" void kernel_launch(void* const* d_in, const int* in_sizes, int n_in,
                              void* d_out, int out_size, void* d_ws, size_t ws_size,
                              hipStream_t stream) {
    const float* pooler = (const float*)d_in[0];
    const float* lhs    = (const float*)d_in[1];
    const float* mask   = (const float*)d_in[2];
    const float* am     = (const float*)d_in[3];
    const float* ctc    = (const float*)d_in[4];
    const float* labels = (const float*)d_in[5];
    const float* W      = (const float*)d_in[6];
    const float* bb     = (const float*)d_in[7];
    const int*   nbest  = (const int*)d_in[8];

    const int N = in_sizes[5];            // labels: (N,)
    const int B = in_sizes[8];            // nBestIndex: (B,)
    const int H = in_sizes[0] / N;        // pooler: (N, H)
    const int S = in_sizes[2] / N;        // attention_mask: (N, S)

    float* out  = (float*)d_out;
    float* loss = out + N;

    float* pooled = (float*)d_ws;
    int*   starts = (int*)((char*)d_ws + (size_t)N * H * sizeof(float));
    int*   seg    = starts + (B + 1);

    hipLaunchKernelGGL(pool_kernel, dim3(N), dim3(H / 4), 0, stream,
                       lhs, mask, pooled, S, H);
    hipLaunchKernelGGL(score_kernel, dim3((N + 3) / 4), dim3(256), 0, stream,
                       pooler, am, ctc, W, bb, out, N, H);
    hipLaunchKernelGGL(seg_starts_kernel, dim3(1), dim3(64), 0, stream,
                       nbest, starts, loss, B);
    hipLaunchKernelGGL(seg_fill_kernel, dim3(B), dim3(64), 0, stream,
                       starts, seg);
    hipLaunchKernelGGL(ce_kernel, dim3(B), dim3(64), 0, stream,
                       out, labels, starts, loss, N);
    hipLaunchKernelGGL(contrast_kernel, dim3(N), dim3(256), 0, stream,
                       pooler, pooled, starts, seg, loss, H, B);
}

// Round 2
// 356.937 us; speedup vs baseline: 1.0820x; 1.0820x over previous
//
#include <hip/hip_runtime.h>
#include <math.h>

typedef float f32x4 __attribute__((ext_vector_type(4)));

// out layout: d_out[0..N) = final_score (f32), d_out[N] = loss (f32)
// ws layout:  pooled f32[N*H] | starts i32[B+1] | seg i32[N]

// ---------------- Kernel A: group starts + seg ids + loss=0 (1 block) ----
__global__ void seg_kernel(const int* __restrict__ nbest,
                           int* __restrict__ starts, int* __restrict__ seg,
                           float* __restrict__ loss, int B) {
    __shared__ int s_starts[1025];          // supports B <= 1024
    if (threadIdx.x == 0) {
        int off = 0;
        for (int g = 0; g < B; ++g) { s_starts[g] = off; starts[g] = off; off += nbest[g]; }
        s_starts[B] = off; starts[B] = off;
        *loss = 0.f;
    }
    __syncthreads();
    for (int g = 0; g < B; ++g) {
        const int s0 = s_starts[g], s1 = s_starts[g + 1];
        for (int i = s0 + (int)threadIdx.x; i < s1; i += blockDim.x) seg[i] = g;
    }
}

// ---------------- Kernel B: masked avg-pool + per-row linear score -------
// grid = N blocks, block = H/4 threads (192 for H=768).
// Pure streaming read of lhs (nontemporal float4), mask staged in LDS.
__global__ void poolscore_kernel(const float* __restrict__ lhs,
                                 const float* __restrict__ mask,
                                 const float* __restrict__ pooler,
                                 const float* __restrict__ am,
                                 const float* __restrict__ ctc,
                                 const float* __restrict__ W,
                                 const float* __restrict__ bb,
                                 float* __restrict__ pooled,
                                 float* __restrict__ score,
                                 int S, int H) {
    __shared__ float smask[1024];           // supports S <= 1024
    const int j  = blockIdx.x;
    const int t  = threadIdx.x;             // 0 .. H/4-1
    const int Hv = H >> 2;

    // stage mask row in LDS once
    const float* mrow = mask + (size_t)j * S;
    for (int s = t; s < S; s += blockDim.x) smask[s] = mrow[s];
    __syncthreads();

    // mask sum (LDS broadcast reads, identical across threads)
    float msum = 0.f;
    for (int s = 0; s < S; ++s) msum += smask[s];

    // main stream: one float4 per lane per s, nontemporal (read-once data)
    const f32x4* row = (const f32x4*)(lhs + (size_t)j * S * H);
    f32x4 acc = {0.f, 0.f, 0.f, 0.f};
#pragma unroll 8
    for (int s = 0; s < S; ++s) {
        f32x4 v = __builtin_nontemporal_load(&row[(size_t)s * Hv + t]);
        acc += v * smask[s];
    }
    const f32x4 o = acc * (1.0f / msum);
    ((f32x4*)(pooled + (size_t)j * H))[t] = o;

    // --- fused score: wave 0 computes [pooler_j, am_j, ctc_j] @ W + b ----
    if (t < 64) {
        const f32x4* pr = (const f32x4*)(pooler + (size_t)j * H);
        const f32x4* Wv = (const f32x4*)W;
        float a = 0.f;
        for (int k = t; k < Hv; k += 64) {
            f32x4 p = pr[k] * Wv[k];
            a += p.x + p.y + p.z + p.w;
        }
        for (int d = 32; d > 0; d >>= 1) a += __shfl_xor(a, d, 64);
        if (t == 0)
            score[j] = a + am[j] * W[H] + ctc[j] * W[H + 1] + bb[0];
    }
}

// ---------------- Kernel C: contrast loss (diag only) + fused CE ---------
// blocks [0,N): contrast for row i.  blocks [N,N+B): CE for group g=i-N.
__global__ void finale_kernel(const float* __restrict__ pooler,
                              const float* __restrict__ pooled,
                              const float* __restrict__ score,
                              const float* __restrict__ labels,
                              const int* __restrict__ starts,
                              const int* __restrict__ seg,
                              float* __restrict__ loss,
                              int H, int N, int B) {
    const int bid = blockIdx.x;
    if (bid >= N) {
        // ----- CE for group g, one wave -----
        const int g = bid - N;
        const int lane = threadIdx.x;
        if (lane >= 64) return;
        const int s0 = starts[g], sz = starts[g + 1] - s0;
        float m = -INFINITY;
        for (int idx = lane; idx < sz; idx += 64) m = fmaxf(m, score[s0 + idx]);
        for (int d = 32; d > 0; d >>= 1) m = fmaxf(m, __shfl_xor(m, d, 64));
        float s = 0.f;
        for (int idx = lane; idx < sz; idx += 64) s += expf(score[s0 + idx] - m);
        for (int d = 32; d > 0; d >>= 1) s += __shfl_xor(s, d, 64);
        const float ls = logf(s);
        float c = 0.f;
        for (int idx = lane; idx < sz; idx += 64) {
            float lb = labels[s0 + idx];
            if (lb != 0.f) c += lb * (score[s0 + idx] - m - ls);
        }
        for (int d = 32; d > 0; d >>= 1) c += __shfl_xor(c, d, 64);
        if (lane == 0) atomicAdd(loss, -c / (float)N);
        return;
    }
    // ----- contrast for row i: only sim[i, j] within i's group matters ---
    __shared__ float simv[512];             // supports group size <= 512
    const int i  = bid;
    const int g  = seg[i];
    const int s0 = starts[g], sz = starts[g + 1] - s0;
    const int wid = threadIdx.x >> 6, lane = threadIdx.x & 63;
    const int nw  = blockDim.x >> 6;
    const int Hv  = H >> 2;
    const f32x4* pi = (const f32x4*)(pooler + (size_t)i * H);
    for (int j = wid; j < sz; j += nw) {
        const f32x4* pj = (const f32x4*)(pooled + (size_t)(s0 + j) * H);
        float acc = 0.f;
        for (int k = lane; k < Hv; k += 64) {
            f32x4 p = pi[k] * pj[k];
            acc += p.x + p.y + p.z + p.w;
        }
        for (int d = 32; d > 0; d >>= 1) acc += __shfl_xor(acc, d, 64);
        if (lane == 0) simv[j] = acc;
    }
    __syncthreads();
    if (wid == 0) {
        float m = -INFINITY;
        for (int idx = lane; idx < sz; idx += 64) m = fmaxf(m, simv[idx]);
        for (int d = 32; d > 0; d >>= 1) m = fmaxf(m, __shfl_xor(m, d, 64));
        float s = 0.f;
        for (int idx = lane; idx < sz; idx += 64) s += expf(simv[idx] - m);
        for (int d = 32; d > 0; d >>= 1) s += __shfl_xor(s, d, 64);
        if (lane == 0) {
            const int p = i - s0;           // diagonal position within group
            const float prob = expf(simv[p] - m) / s;
            atomicAdd(loss, -prob / (float)B);
        }
    }
}

extern "C" void kernel_launch(void* const* d_in, const int* in_sizes, int n_in,
                              void* d_out, int out_size, void* d_ws, size_t ws_size,
                              hipStream_t stream) {
    const float* pooler = (const float*)d_in[0];
    const float* lhs    = (const float*)d_in[1];
    const float* mask   = (const float*)d_in[2];
    const float* am     = (const float*)d_in[3];
    const float* ctc    = (const float*)d_in[4];
    const float* labels = (const float*)d_in[5];
    const float* W      = (const float*)d_in[6];
    const float* bb     = (const float*)d_in[7];
    const int*   nbest  = (const int*)d_in[8];

    const int N = in_sizes[5];            // labels: (N,)
    const int B = in_sizes[8];            // nBestIndex: (B,)
    const int H = in_sizes[0] / N;        // pooler: (N, H)
    const int S = in_sizes[2] / N;        // attention_mask: (N, S)

    float* out  = (float*)d_out;
    float* loss = out + N;

    float* pooled = (float*)d_ws;
    int*   starts = (int*)((char*)d_ws + (size_t)N * H * sizeof(float));
    int*   seg    = starts + (B + 1);

    hipLaunchKernelGGL(seg_kernel, dim3(1), dim3(256), 0, stream,
                       nbest, starts, seg, loss, B);
    hipLaunchKernelGGL(poolscore_kernel, dim3(N), dim3(H / 4), 0, stream,
                       lhs, mask, pooler, am, ctc, W, bb, pooled, out, S, H);
    hipLaunchKernelGGL(finale_kernel, dim3(N + B), dim3(256), 0, stream,
                       pooler, pooled, out, labels, starts, seg, loss, H, N, B);
}

// Round 3
// 327.625 us; speedup vs baseline: 1.1788x; 1.0895x over previous
//
#include <hip/hip_runtime.h>
#include <math.h>

typedef float f32x4 __attribute__((ext_vector_type(4)));

// out layout: d_out[0..N) = final_score (f32), d_out[N] = loss (f32)
// ws layout:  pooled f32[N*H] | starts i32[B+1] | seg i32[N]

// ---------------- Kernel A: group starts + seg ids + loss=0 (1 block) ----
__global__ void seg_kernel(const int* __restrict__ nbest,
                           int* __restrict__ starts, int* __restrict__ seg,
                           float* __restrict__ loss, int B) {
    __shared__ int sh[1025];                // supports B <= 1024
    const int t = threadIdx.x;
    for (int g = t; g < B; g += blockDim.x) sh[g] = nbest[g];
    __syncthreads();
    if (t == 0) {                           // short LDS-only scan
        int off = 0;
        for (int g = 0; g < B; ++g) { int v = sh[g]; sh[g] = off; off += v; }
        sh[B] = off;
        *loss = 0.f;
    }
    __syncthreads();
    for (int g = t; g <= B; g += blockDim.x) starts[g] = sh[g];
    // fill per-row segment id: thread per group, rows within group serial
    for (int g = t; g < B; g += blockDim.x) {
        const int s0 = sh[g], s1 = sh[g + 1];
        for (int i = s0; i < s1; ++i) seg[i] = g;
    }
}

// ---------------- Kernel B: wave-per-row masked avg-pool + linear score --
// Specialized for H == 768 (Hv=192 = 3 chunks of 64 f32x4 per wave).
// 256-thread blocks = 4 waves; wave w of block b owns row j = b*4+w.
__global__ __launch_bounds__(256, 4)
void pool_kernel_h768(const float* __restrict__ lhs,
                      const float* __restrict__ mask,
                      const float* __restrict__ pooler,
                      const float* __restrict__ am,
                      const float* __restrict__ ctc,
                      const float* __restrict__ W,
                      const float* __restrict__ bb,
                      float* __restrict__ pooled,
                      float* __restrict__ score,
                      int N, int S) {
    const int H  = 768;
    const int Hv = 192;
    const int wid  = threadIdx.x >> 6;
    const int lane = threadIdx.x & 63;
    const int j = blockIdx.x * 4 + wid;
    if (j >= N) return;

    const f32x4* row  = (const f32x4*)(lhs + (size_t)j * S * H) + lane;
    const float* mrow = mask + (size_t)j * S;

    f32x4 a0 = {0.f,0.f,0.f,0.f}, a1 = a0, a2 = a0;
    float msum = 0.f;
#pragma unroll 8
    for (int s = 0; s < S; ++s) {
        float m = mrow[s];                  // wave-uniform addr -> 1 req/wave
        const f32x4* p = row + (size_t)s * Hv;
        f32x4 v0 = __builtin_nontemporal_load(p);
        f32x4 v1 = __builtin_nontemporal_load(p + 64);
        f32x4 v2 = __builtin_nontemporal_load(p + 128);
        a0 += v0 * m; a1 += v1 * m; a2 += v2 * m;
        msum += m;
    }
    const float inv = 1.0f / msum;
    f32x4* prow = (f32x4*)(pooled + (size_t)j * H);
    prow[lane]       = a0 * inv;
    prow[lane + 64]  = a1 * inv;
    prow[lane + 128] = a2 * inv;

    // fused score: this wave computes [pooler_j, am_j, ctc_j] @ W + b
    const f32x4* pr = (const f32x4*)(pooler + (size_t)j * H);
    const f32x4* Wv = (const f32x4*)W;
    float acc = 0.f;
#pragma unroll
    for (int k = lane; k < Hv; k += 64) {
        f32x4 p = pr[k] * Wv[k];
        acc += p.x + p.y + p.z + p.w;
    }
    for (int d = 32; d > 0; d >>= 1) acc += __shfl_xor(acc, d, 64);
    if (lane == 0)
        score[j] = acc + am[j] * W[H] + ctc[j] * W[H + 1] + bb[0];
}

// ---------------- Kernel B': generic fallback (block per row) ------------
__global__ void pool_kernel_generic(const float* __restrict__ lhs,
                                    const float* __restrict__ mask,
                                    const float* __restrict__ pooler,
                                    const float* __restrict__ am,
                                    const float* __restrict__ ctc,
                                    const float* __restrict__ W,
                                    const float* __restrict__ bb,
                                    float* __restrict__ pooled,
                                    float* __restrict__ score,
                                    int S, int H) {
    const int j  = blockIdx.x;
    const int t  = threadIdx.x;
    const int Hv = H >> 2;
    const f32x4* row  = (const f32x4*)(lhs + (size_t)j * S * H);
    const float* mrow = mask + (size_t)j * S;
    f32x4 acc = {0.f,0.f,0.f,0.f};
    float msum = 0.f;
#pragma unroll 4
    for (int s = 0; s < S; ++s) {
        float m = mrow[s];
        acc += __builtin_nontemporal_load(&row[(size_t)s * Hv + t]) * m;
        msum += m;
    }
    ((f32x4*)(pooled + (size_t)j * H))[t] = acc * (1.0f / msum);
    if (t < 64) {
        const f32x4* pr = (const f32x4*)(pooler + (size_t)j * H);
        const f32x4* Wv = (const f32x4*)W;
        float a = 0.f;
        for (int k = t; k < Hv; k += 64) {
            f32x4 p = pr[k] * Wv[k];
            a += p.x + p.y + p.z + p.w;
        }
        for (int d = 32; d > 0; d >>= 1) a += __shfl_xor(a, d, 64);
        if (t == 0)
            score[j] = a + am[j] * W[H] + ctc[j] * W[H + 1] + bb[0];
    }
}

// ---------------- Kernel C: contrast loss (diag only) + fused CE ---------
__global__ void finale_kernel(const float* __restrict__ pooler,
                              const float* __restrict__ pooled,
                              const float* __restrict__ score,
                              const float* __restrict__ labels,
                              const int* __restrict__ starts,
                              const int* __restrict__ seg,
                              float* __restrict__ loss,
                              int H, int N, int B) {
    const int bid = blockIdx.x;
    if (bid >= N) {
        // ----- CE for group g, one wave -----
        const int g = bid - N;
        const int lane = threadIdx.x;
        if (lane >= 64) return;
        const int s0 = starts[g], sz = starts[g + 1] - s0;
        float m = -INFINITY;
        for (int idx = lane; idx < sz; idx += 64) m = fmaxf(m, score[s0 + idx]);
        for (int d = 32; d > 0; d >>= 1) m = fmaxf(m, __shfl_xor(m, d, 64));
        float s = 0.f;
        for (int idx = lane; idx < sz; idx += 64) s += expf(score[s0 + idx] - m);
        for (int d = 32; d > 0; d >>= 1) s += __shfl_xor(s, d, 64);
        const float ls = logf(s);
        float c = 0.f;
        for (int idx = lane; idx < sz; idx += 64) {
            float lb = labels[s0 + idx];
            if (lb != 0.f) c += lb * (score[s0 + idx] - m - ls);
        }
        for (int d = 32; d > 0; d >>= 1) c += __shfl_xor(c, d, 64);
        if (lane == 0) atomicAdd(loss, -c / (float)N);
        return;
    }
    // ----- contrast for row i: only sim[i, j] within i's group matters ---
    __shared__ float simv[512];             // supports group size <= 512
    const int i  = bid;
    const int g  = seg[i];
    const int s0 = starts[g], sz = starts[g + 1] - s0;
    const int wid = threadIdx.x >> 6, lane = threadIdx.x & 63;
    const int nw  = blockDim.x >> 6;
    const int Hv  = H >> 2;
    const f32x4* pi = (const f32x4*)(pooler + (size_t)i * H);
    for (int j = wid; j < sz; j += nw) {
        const f32x4* pj = (const f32x4*)(pooled + (size_t)(s0 + j) * H);
        float acc = 0.f;
        for (int k = lane; k < Hv; k += 64) {
            f32x4 p = pi[k] * pj[k];
            acc += p.x + p.y + p.z + p.w;
        }
        for (int d = 32; d > 0; d >>= 1) acc += __shfl_xor(acc, d, 64);
        if (lane == 0) simv[j] = acc;
    }
    __syncthreads();
    if (wid == 0) {
        float m = -INFINITY;
        for (int idx = lane; idx < sz; idx += 64) m = fmaxf(m, simv[idx]);
        for (int d = 32; d > 0; d >>= 1) m = fmaxf(m, __shfl_xor(m, d, 64));
        float s = 0.f;
        for (int idx = lane; idx < sz; idx += 64) s += expf(simv[idx] - m);
        for (int d = 32; d > 0; d >>= 1) s += __shfl_xor(s, d, 64);
        if (lane == 0) {
            const int p = i - s0;           // diagonal position within group
            const float prob = expf(simv[p] - m) / s;
            atomicAdd(loss, -prob / (float)B);
        }
    }
}

extern "C" void kernel_launch(void* const* d_in, const int* in_sizes, int n_in,
                              void* d_out, int out_size, void* d_ws, size_t ws_size,
                              hipStream_t stream) {
    const float* pooler = (const float*)d_in[0];
    const float* lhs    = (const float*)d_in[1];
    const float* mask   = (const float*)d_in[2];
    const float* am     = (const float*)d_in[3];
    const float* ctc    = (const float*)d_in[4];
    const float* labels = (const float*)d_in[5];
    const float* W      = (const float*)d_in[6];
    const float* bb     = (const float*)d_in[7];
    const int*   nbest  = (const int*)d_in[8];

    const int N = in_sizes[5];            // labels: (N,)
    const int B = in_sizes[8];            // nBestIndex: (B,)
    const int H = in_sizes[0] / N;        // pooler: (N, H)
    const int S = in_sizes[2] / N;        // attention_mask: (N, S)

    float* out  = (float*)d_out;
    float* loss = out + N;

    float* pooled = (float*)d_ws;
    int*   starts = (int*)((char*)d_ws + (size_t)N * H * sizeof(float));
    int*   seg    = starts + (B + 1);

    hipLaunchKernelGGL(seg_kernel, dim3(1), dim3(256), 0, stream,
                       nbest, starts, seg, loss, B);
    if (H == 768) {
        hipLaunchKernelGGL(pool_kernel_h768, dim3((N + 3) / 4), dim3(256), 0,
                           stream, lhs, mask, pooler, am, ctc, W, bb,
                           pooled, out, N, S);
    } else {
        hipLaunchKernelGGL(pool_kernel_generic, dim3(N), dim3(H / 4), 0,
                           stream, lhs, mask, pooler, am, ctc, W, bb,
                           pooled, out, S, H);
    }
    hipLaunchKernelGGL(finale_kernel, dim3(N + B), dim3(256), 0, stream,
                       pooler, pooled, out, labels, starts, seg, loss, H, N, B);
}

// Round 4
// 304.558 us; speedup vs baseline: 1.2681x; 1.0757x over previous
//
#include <hip/hip_runtime.h>
#include <math.h>

typedef float f32x4 __attribute__((ext_vector_type(4)));

// out layout: d_out[0..N) = final_score (f32), d_out[N] = loss (f32)
// ws layout (H==768 fast path): pooled f32[N*H]
// ws layout (generic path):     pooled f32[N*H] | starts i32[B+1] | seg i32[N]

// ---------------- Kernel B: wave-per-row masked avg-pool + linear score --
// Specialized for H == 768 (Hv=192 = 3 chunks of 64 f32x4 per wave).
// 256-thread blocks = 4 waves; wave w of block b owns row j = b*4+w.
__global__ __launch_bounds__(256, 4)
void pool_kernel_h768(const float* __restrict__ lhs,
                      const float* __restrict__ mask,
                      const float* __restrict__ pooler,
                      const float* __restrict__ am,
                      const float* __restrict__ ctc,
                      const float* __restrict__ W,
                      const float* __restrict__ bb,
                      float* __restrict__ pooled,
                      float* __restrict__ score,
                      int N, int S) {
    const int H  = 768;
    const int Hv = 192;
    // zero the loss slot (score[N]); group_kernel runs after us in-stream
    if (blockIdx.x == 0 && threadIdx.x == 0) score[N] = 0.f;

    const int wid  = threadIdx.x >> 6;
    const int lane = threadIdx.x & 63;
    const int j = blockIdx.x * 4 + wid;
    if (j >= N) return;

    const f32x4* row  = (const f32x4*)(lhs + (size_t)j * S * H) + lane;
    const float* mrow = mask + (size_t)j * S;

    f32x4 a0 = {0.f,0.f,0.f,0.f}, a1 = a0, a2 = a0;
    float msum = 0.f;
#pragma unroll 8
    for (int s = 0; s < S; ++s) {
        float m = mrow[s];                  // wave-uniform addr -> 1 req/wave
        const f32x4* p = row + (size_t)s * Hv;
        f32x4 v0 = __builtin_nontemporal_load(p);
        f32x4 v1 = __builtin_nontemporal_load(p + 64);
        f32x4 v2 = __builtin_nontemporal_load(p + 128);
        a0 += v0 * m; a1 += v1 * m; a2 += v2 * m;
        msum += m;
    }
    const float inv = 1.0f / msum;
    f32x4* prow = (f32x4*)(pooled + (size_t)j * H);
    prow[lane]       = a0 * inv;
    prow[lane + 64]  = a1 * inv;
    prow[lane + 128] = a2 * inv;

    // fused score: this wave computes [pooler_j, am_j, ctc_j] @ W + b
    const f32x4* pr = (const f32x4*)(pooler + (size_t)j * H);
    const f32x4* Wv = (const f32x4*)W;
    float acc = 0.f;
#pragma unroll
    for (int k = lane; k < Hv; k += 64) {
        f32x4 p = pr[k] * Wv[k];
        acc += p.x + p.y + p.z + p.w;
    }
    for (int d = 32; d > 0; d >>= 1) acc += __shfl_xor(acc, d, 64);
    if (lane == 0)
        score[j] = acc + am[j] * W[H] + ctc[j] * W[H + 1] + bb[0];
}

// ---------------- Kernel C (H==768): one block per n-best group ----------
// Stages the group's pooled rows in LDS, computes the group sim sub-matrix
// with lane-owns-j full-register dots, softmax per row, diag -> contrast;
// fused CE; exactly ONE global atomicAdd per block.
#define MAX_ROWS 40
#define PADV 193          // f32x4 units per LDS row (772 f32 -> 4-way max)

__global__ __launch_bounds__(256)
void group_kernel(const float* __restrict__ pooler,
                  const float* __restrict__ pooled,
                  const float* __restrict__ score,
                  const float* __restrict__ labels,
                  const int* __restrict__ nbest,
                  float* __restrict__ loss,
                  int N, int B) {
    __shared__ f32x4 s_pool[MAX_ROWS * PADV];   // ~123.5 KB
    __shared__ int   s_nb[1024];
    __shared__ int   sh_s0, sh_sz;
    __shared__ float blk_loss;

    const int g = blockIdx.x;
    const int t = threadIdx.x;

    for (int i = t; i < B; i += 256) s_nb[i] = nbest[i];
    __syncthreads();
    if (t == 0) {
        int off = 0;
        for (int i = 0; i < g; ++i) off += s_nb[i];
        sh_s0 = off; sh_sz = s_nb[g];
        blk_loss = 0.f;
    }
    __syncthreads();
    const int s0 = sh_s0, sz = sh_sz;

    const f32x4* pooled4 = (const f32x4*)pooled;
    const bool staged = (sz <= MAX_ROWS);
    if (staged) {
        for (int idx = t; idx < sz * 192; idx += 256) {
            int r = idx / 192, c = idx - r * 192;
            s_pool[r * PADV + c] = pooled4[(size_t)(s0 + r) * 192 + c];
        }
    }
    __syncthreads();

    const int wid  = t >> 6;
    const int lane = t & 63;
    const f32x4* jbase  = staged ? s_pool : (pooled4 + (size_t)s0 * 192);
    const int    jstride = staged ? PADV : 192;

    if (sz <= 32) {
        // two rows per wave-pass: lanes 0-31 row r, lanes 32-63 row r+4
        const int jj = lane & 31, half = lane >> 5;
        for (int p = 0; wid + 8 * p < sz; ++p) {
            const int  r   = wid + 8 * p + 4 * half;
            const bool rok = (r < sz);
            const bool jok = (jj < sz);
            const f32x4* pi = (const f32x4*)(pooler + (size_t)(s0 + (rok ? r : 0)) * 768);
            const f32x4* pj = jbase + (size_t)(jok ? jj : 0) * jstride;
            f32x4 accA = {0.f,0.f,0.f,0.f}, accB = accA;
#pragma unroll 4
            for (int k = 0; k < 192; k += 2) {
                accA += pi[k]     * pj[k];
                accB += pi[k + 1] * pj[k + 1];
            }
            f32x4 acc4 = accA + accB;
            float val = (rok && jok) ? (acc4.x + acc4.y + acc4.z + acc4.w)
                                     : -INFINITY;
            float m = val;
            for (int d = 1; d < 32; d <<= 1) m = fmaxf(m, __shfl_xor(m, d, 64));
            float e = (rok && jok) ? expf(val - m) : 0.f;
            float ssum = e;
            for (int d = 1; d < 32; d <<= 1) ssum += __shfl_xor(ssum, d, 64);
            if (rok && jok && jj == r)
                atomicAdd(&blk_loss, -(e / ssum) / (float)B);
        }
    } else if (sz <= 64) {
        // one row per wave-pass, lane owns j
        for (int r = wid; r < sz; r += 4) {
            const bool jok = (lane < sz);
            const f32x4* pi = (const f32x4*)(pooler + (size_t)(s0 + r) * 768);
            const f32x4* pj = jbase + (size_t)(jok ? lane : 0) * jstride;
            f32x4 accA = {0.f,0.f,0.f,0.f}, accB = accA;
#pragma unroll 4
            for (int k = 0; k < 192; k += 2) {
                accA += pi[k]     * pj[k];
                accB += pi[k + 1] * pj[k + 1];
            }
            f32x4 acc4 = accA + accB;
            float val = jok ? (acc4.x + acc4.y + acc4.z + acc4.w) : -INFINITY;
            float m = val;
            for (int d = 1; d < 64; d <<= 1) m = fmaxf(m, __shfl_xor(m, d, 64));
            float e = jok ? expf(val - m) : 0.f;
            float ssum = e;
            for (int d = 1; d < 64; d <<= 1) ssum += __shfl_xor(ssum, d, 64);
            if (jok && lane == r)
                atomicAdd(&blk_loss, -(e / ssum) / (float)B);
        }
    } else {
        // generic chunked online-softmax fallback (slow path, unstaged)
        for (int r = wid; r < sz; r += 4) {
            const f32x4* pi = (const f32x4*)(pooler + (size_t)(s0 + r) * 768);
            float mrun = -INFINITY, srun = 0.f, dval = 0.f;
            for (int jc = 0; jc < sz; jc += 64) {
                const int  j   = jc + lane;
                const bool jok = (j < sz);
                const f32x4* pj = pooled4 + (size_t)(s0 + (jok ? j : 0)) * 192;
                f32x4 accA = {0.f,0.f,0.f,0.f}, accB = accA;
                for (int k = 0; k < 192; k += 2) {
                    accA += pi[k]     * pj[k];
                    accB += pi[k + 1] * pj[k + 1];
                }
                f32x4 acc4 = accA + accB;
                float val = jok ? (acc4.x + acc4.y + acc4.z + acc4.w) : -INFINITY;
                float cm = val;
                for (int d = 1; d < 64; d <<= 1) cm = fmaxf(cm, __shfl_xor(cm, d, 64));
                float e = jok ? expf(val - cm) : 0.f;
                float cs = e;
                for (int d = 1; d < 64; d <<= 1) cs += __shfl_xor(cs, d, 64);
                float nm = fmaxf(mrun, cm);
                srun = srun * expf(mrun - nm) + cs * expf(cm - nm);
                float dv = __shfl(val, r - jc, 64);   // valid iff diag in chunk
                if (r >= jc && r < jc + 64) dval = dv;
                mrun = nm;
            }
            if (lane == 0)
                atomicAdd(&blk_loss, -(expf(dval - mrun) / srun) / (float)B);
        }
    }

    __syncthreads();
    // fused CE for this group (wave 0)
    if (wid == 0) {
        float m = -INFINITY;
        for (int idx = lane; idx < sz; idx += 64) m = fmaxf(m, score[s0 + idx]);
        for (int d = 1; d < 64; d <<= 1) m = fmaxf(m, __shfl_xor(m, d, 64));
        float s = 0.f;
        for (int idx = lane; idx < sz; idx += 64) s += expf(score[s0 + idx] - m);
        for (int d = 1; d < 64; d <<= 1) s += __shfl_xor(s, d, 64);
        const float ls = logf(s);
        float c = 0.f;
        for (int idx = lane; idx < sz; idx += 64) {
            float lb = labels[s0 + idx];
            if (lb != 0.f) c += lb * (score[s0 + idx] - m - ls);
        }
        for (int d = 1; d < 64; d <<= 1) c += __shfl_xor(c, d, 64);
        if (lane == 0) atomicAdd(&blk_loss, -c / (float)N);
    }
    __syncthreads();
    if (t == 0) atomicAdd(loss, blk_loss);
}

// =================== generic fallback path (H != 768) ====================
__global__ void seg_kernel(const int* __restrict__ nbest,
                           int* __restrict__ starts, int* __restrict__ seg,
                           float* __restrict__ loss, int B) {
    __shared__ int sh[1025];
    const int t = threadIdx.x;
    for (int g = t; g < B; g += blockDim.x) sh[g] = nbest[g];
    __syncthreads();
    if (t == 0) {
        int off = 0;
        for (int g = 0; g < B; ++g) { int v = sh[g]; sh[g] = off; off += v; }
        sh[B] = off;
        *loss = 0.f;
    }
    __syncthreads();
    for (int g = t; g <= B; g += blockDim.x) starts[g] = sh[g];
    for (int g = t; g < B; g += blockDim.x) {
        const int s0 = sh[g], s1 = sh[g + 1];
        for (int i = s0; i < s1; ++i) seg[i] = g;
    }
}

__global__ void pool_kernel_generic(const float* __restrict__ lhs,
                                    const float* __restrict__ mask,
                                    const float* __restrict__ pooler,
                                    const float* __restrict__ am,
                                    const float* __restrict__ ctc,
                                    const float* __restrict__ W,
                                    const float* __restrict__ bb,
                                    float* __restrict__ pooled,
                                    float* __restrict__ score,
                                    int S, int H) {
    const int j  = blockIdx.x;
    const int t  = threadIdx.x;
    const int Hv = H >> 2;
    const f32x4* row  = (const f32x4*)(lhs + (size_t)j * S * H);
    const float* mrow = mask + (size_t)j * S;
    f32x4 acc = {0.f,0.f,0.f,0.f};
    float msum = 0.f;
#pragma unroll 4
    for (int s = 0; s < S; ++s) {
        float m = mrow[s];
        acc += __builtin_nontemporal_load(&row[(size_t)s * Hv + t]) * m;
        msum += m;
    }
    ((f32x4*)(pooled + (size_t)j * H))[t] = acc * (1.0f / msum);
    if (t < 64) {
        const f32x4* pr = (const f32x4*)(pooler + (size_t)j * H);
        const f32x4* Wv = (const f32x4*)W;
        float a = 0.f;
        for (int k = t; k < Hv; k += 64) {
            f32x4 p = pr[k] * Wv[k];
            a += p.x + p.y + p.z + p.w;
        }
        for (int d = 32; d > 0; d >>= 1) a += __shfl_xor(a, d, 64);
        if (t == 0)
            score[j] = a + am[j] * W[H] + ctc[j] * W[H + 1] + bb[0];
    }
}

__global__ void finale_kernel(const float* __restrict__ pooler,
                              const float* __restrict__ pooled,
                              const float* __restrict__ score,
                              const float* __restrict__ labels,
                              const int* __restrict__ starts,
                              const int* __restrict__ seg,
                              float* __restrict__ loss,
                              int H, int N, int B) {
    const int bid = blockIdx.x;
    if (bid >= N) {
        const int g = bid - N;
        const int lane = threadIdx.x;
        if (lane >= 64) return;
        const int s0 = starts[g], sz = starts[g + 1] - s0;
        float m = -INFINITY;
        for (int idx = lane; idx < sz; idx += 64) m = fmaxf(m, score[s0 + idx]);
        for (int d = 32; d > 0; d >>= 1) m = fmaxf(m, __shfl_xor(m, d, 64));
        float s = 0.f;
        for (int idx = lane; idx < sz; idx += 64) s += expf(score[s0 + idx] - m);
        for (int d = 32; d > 0; d >>= 1) s += __shfl_xor(s, d, 64);
        const float ls = logf(s);
        float c = 0.f;
        for (int idx = lane; idx < sz; idx += 64) {
            float lb = labels[s0 + idx];
            if (lb != 0.f) c += lb * (score[s0 + idx] - m - ls);
        }
        for (int d = 32; d > 0; d >>= 1) c += __shfl_xor(c, d, 64);
        if (lane == 0) atomicAdd(loss, -c / (float)N);
        return;
    }
    __shared__ float simv[512];
    const int i  = bid;
    const int g  = seg[i];
    const int s0 = starts[g], sz = starts[g + 1] - s0;
    const int wid = threadIdx.x >> 6, lane = threadIdx.x & 63;
    const int nw  = blockDim.x >> 6;
    const int Hv  = H >> 2;
    const f32x4* pi = (const f32x4*)(pooler + (size_t)i * H);
    for (int j = wid; j < sz; j += nw) {
        const f32x4* pj = (const f32x4*)(pooled + (size_t)(s0 + j) * H);
        float acc = 0.f;
        for (int k = lane; k < Hv; k += 64) {
            f32x4 p = pi[k] * pj[k];
            acc += p.x + p.y + p.z + p.w;
        }
        for (int d = 32; d > 0; d >>= 1) acc += __shfl_xor(acc, d, 64);
        if (lane == 0) simv[j] = acc;
    }
    __syncthreads();
    if (wid == 0) {
        float m = -INFINITY;
        for (int idx = lane; idx < sz; idx += 64) m = fmaxf(m, simv[idx]);
        for (int d = 32; d > 0; d >>= 1) m = fmaxf(m, __shfl_xor(m, d, 64));
        float s = 0.f;
        for (int idx = lane; idx < sz; idx += 64) s += expf(simv[idx] - m);
        for (int d = 32; d > 0; d >>= 1) s += __shfl_xor(s, d, 64);
        if (lane == 0) {
            const int p = i - s0;
            const float prob = expf(simv[p] - m) / s;
            atomicAdd(loss, -prob / (float)B);
        }
    }
}

extern "C" void kernel_launch(void* const* d_in, const int* in_sizes, int n_in,
                              void* d_out, int out_size, void* d_ws, size_t ws_size,
                              hipStream_t stream) {
    const float* pooler = (const float*)d_in[0];
    const float* lhs    = (const float*)d_in[1];
    const float* mask   = (const float*)d_in[2];
    const float* am     = (const float*)d_in[3];
    const float* ctc    = (const float*)d_in[4];
    const float* labels = (const float*)d_in[5];
    const float* W      = (const float*)d_in[6];
    const float* bb     = (const float*)d_in[7];
    const int*   nbest  = (const int*)d_in[8];

    const int N = in_sizes[5];            // labels: (N,)
    const int B = in_sizes[8];            // nBestIndex: (B,)
    const int H = in_sizes[0] / N;        // pooler: (N, H)
    const int S = in_sizes[2] / N;        // attention_mask: (N, S)

    float* out  = (float*)d_out;
    float* loss = out + N;
    float* pooled = (float*)d_ws;

    if (H == 768) {
        hipLaunchKernelGGL(pool_kernel_h768, dim3((N + 3) / 4), dim3(256), 0,
                           stream, lhs, mask, pooler, am, ctc, W, bb,
                           pooled, out, N, S);
        hipLaunchKernelGGL(group_kernel, dim3(B), dim3(256), 0, stream,
                           pooler, pooled, out, labels, nbest, loss, N, B);
    } else {
        int* starts = (int*)((char*)d_ws + (size_t)N * H * sizeof(float));
        int* seg    = starts + (B + 1);
        hipLaunchKernelGGL(seg_kernel, dim3(1), dim3(256), 0, stream,
                           nbest, starts, seg, loss, B);
        hipLaunchKernelGGL(pool_kernel_generic, dim3(N), dim3(H / 4), 0,
                           stream, lhs, mask, pooler, am, ctc, W, bb,
                           pooled, out, S, H);
        hipLaunchKernelGGL(finale_kernel, dim3(N + B), dim3(256), 0, stream,
                           pooler, pooled, out, labels, starts, seg, loss,
                           H, N, B);
    }
}